// Round 9
// baseline (64.742 us; speedup 1.0000x reference)
//
#include <hip/hip_runtime.h>
#include <hip/hip_bf16.h>
#include <stdint.h>

#define N_CELLS 196608
#define NH 9
#define F 64            // F_IN == F_OUT == 64
#define K_TOT (NH * F)  // 576
#define K_STEPS (K_TOT / 32)  // 18
#define NFRAG (K_STEPS * 4)   // 72 B-fragments
#define WLDS_SHORTS (NFRAG * 64 * 8)  // 36864 shorts = 72 KB
#define BLOCK 512              // 8 waves, 32 cells per wave, 256 cells/block

typedef __attribute__((ext_vector_type(8))) short bf16x8;
typedef __attribute__((ext_vector_type(4))) float f32x4;

__device__ inline unsigned short f2bf(float f) {
    union { float f; uint32_t u; } v; v.f = f;
    uint32_t u = v.u;
    uint32_t r = u + 0x7FFFu + ((u >> 16) & 1u);  // round-to-nearest-even
    return (unsigned short)(r >> 16);
}

// ---------------- x: fp32 -> int8 + per-row scale --------------------------
// Row layout PERMUTED so main-kernel lane hi reads one 16B chunk covering
// both K=32 halves: byte pos p = ((k&31)>>3)*16 + (k>>5)*8 + (k&7).
// 16 lanes per row; lane holds 4 consecutive k (same p-block since k%4==0).
__global__ __launch_bounds__(256) void convert_x_i8(
        const float* __restrict__ x, signed char* __restrict__ xq,
        float* __restrict__ stab) {
    int gid = blockIdx.x * blockDim.x + threadIdx.x;
    int row = gid >> 4;
    int k   = (gid & 15) * 4;
    f32x4 v = *reinterpret_cast<const f32x4*>(x + (size_t)row * F + k);
    float m = fmaxf(fmaxf(fabsf(v[0]), fabsf(v[1])),
                    fmaxf(fabsf(v[2]), fabsf(v[3])));
    #pragma unroll
    for (int d = 1; d < 16; d <<= 1) m = fmaxf(m, __shfl_xor(m, d, 64));
    float s  = m * (1.0f / 127.0f);
    float rs = (m > 0.f) ? 127.0f / m : 0.f;
    int p = (((k & 31) >> 3) << 4) + ((k >> 5) << 3) + (k & 7);
    unsigned int d = 0;
    #pragma unroll
    for (int q = 0; q < 4; ++q) {
        int qi = (int)rintf(v[q] * rs);
        d |= ((unsigned int)(qi & 0xff)) << (q * 8);
    }
    *reinterpret_cast<unsigned int*>(xq + (size_t)row * F + p) = d;
    if ((gid & 15) == 0) stab[row] = s;
}

// ---------------- W: fp32 [576][64] -> bf16 MFMA B-fragment layout --------
// frag id = kk*4 + t  (kk = K-step 0..17, t = 16-col tile 0..3)
// lane l holds 8 bf16: B[k = kk*32 + (l>>4)*8 + j][o = t*16 + (l&15)]
__global__ __launch_bounds__(256) void convert_w_kernel(
        const float* __restrict__ W, unsigned short* __restrict__ wb) {
    int tid = blockIdx.x * blockDim.x + threadIdx.x;  // 0 .. 4607
    int l = tid & 63;
    int frag = tid >> 6;          // 0..71
    int kk = frag >> 2, t = frag & 3;
    int k0 = kk * 32 + (l >> 4) * 8;
    int o  = t * 16 + (l & 15);
    unsigned short tmp[8];
    #pragma unroll
    for (int j = 0; j < 8; ++j) tmp[j] = f2bf(W[(size_t)(k0 + j) * F + o]);
    *reinterpret_cast<bf16x8*>(wb + (size_t)tid * 8) =
        *reinterpret_cast<const bf16x8*>(tmp);
}

// ---------------- fused gather + GEMM, v9: int8 gather ---------------------
// v8 post-mortem: every schedule variant pins at ~3.2 TB/s random-fill ->
// bandwidth wall; bytes are the only lever. v9 gathers int8 rows (64B = one
// line, half of bf16), expands to bf16 in VALU (exact ints * per-row scale,
// scale table 0.8MB = L2-resident), then the proven bf16 MFMA path.
// Keeps: fenced depth-2 ring, W-in-LDS (lgkmcnt), 512thr/(512,2) bounds,
// LDS-transpose epilogue for 1KB coalesced stores.
__global__ __launch_bounds__(BLOCK, 2) void fused_gather_gemm_v9(
        const signed char* __restrict__ xq, const float* __restrict__ stab,
        const int* __restrict__ adjc, const unsigned short* __restrict__ wb,
        float* __restrict__ out) {
    __shared__ unsigned short wlds[WLDS_SHORTS];   // 72 KB

    const int wave = threadIdx.x >> 6;
    const int lane = threadIdx.x & 63;
    const int lo = lane & 15, hi = lane >> 4;
    const int wcell = blockIdx.x * 256 + wave * 32;  // wave's 32 cells

    // --- neighbor indices + their row scales (stab is L2-hot, 0.8MB)
    int   idx[2][NH];
    float sc[2][NH];
    #pragma unroll
    for (int m = 0; m < 2; ++m) {
        const int* ap = adjc + (size_t)(wcell + m * 16 + lo) * NH;
        #pragma unroll
        for (int j = 0; j < NH; ++j) idx[m][j] = __builtin_nontemporal_load(ap + j);
        #pragma unroll
        for (int j = 0; j < NH; ++j) sc[m][j] = stab[idx[m][j]];
    }

    // one 16B gather covers both K=32 halves (permuted row layout)
    auto loadA = [&](int m, int j) -> uint4 {
        return *reinterpret_cast<const uint4*>(
                xq + (size_t)idx[m][j] * F + hi * 16);
    };
    // expand 8 int8 (2 dwords) -> bf16x8, scaled
    auto expand = [&](unsigned int d0, unsigned int d1, float s) -> bf16x8 {
        unsigned short tmp[8];
        #pragma unroll
        for (int q = 0; q < 8; ++q) {
            unsigned int dw = (q < 4) ? d0 : d1;
            int c = (int)(signed char)((dw >> ((q & 3) * 8)) & 0xff);
            tmp[q] = f2bf((float)c * s);
        }
        return *reinterpret_cast<const bf16x8*>(tmp);
    };

    // --- stage W into LDS (4608 bf16x8 vectors; 9 per thread, coalesced)
    {
        const bf16x8* src = reinterpret_cast<const bf16x8*>(wb);
        bf16x8* dst = reinterpret_cast<bf16x8*>(wlds);
        #pragma unroll
        for (int it = 0; it < 9; ++it)
            dst[it * BLOCK + threadIdx.x] = src[it * BLOCK + threadIdx.x];
    }

    // --- ring prologue: issue A(0), A(1) (complete during W staging/barrier)
    uint4 aS[3][2];
    #pragma unroll
    for (int m = 0; m < 2; ++m) {
        aS[0][m] = loadA(m, 0);
        aS[1][m] = loadA(m, 1);
    }
    __syncthreads();

    f32x4 acc[2][4];
    #pragma unroll
    for (int m = 0; m < 2; ++m)
        #pragma unroll
        for (int t = 0; t < 4; ++t) acc[m][t] = f32x4{0.f, 0.f, 0.f, 0.f};

    #pragma unroll
    for (int j = 0; j < NH; ++j) {
        const int cur = j % 3;            // compile-time after full unroll
        const int nxt = (j + 2) % 3;
        // Issue slice j+2's 2 gathers; fence pins them above this step's work.
        if (j + 2 < NH) {
            #pragma unroll
            for (int m = 0; m < 2; ++m) aS[nxt][m] = loadA(m, j + 2);
        }
        __builtin_amdgcn_sched_barrier(0);   // loads issued above stay above
        #pragma unroll
        for (int h = 0; h < 2; ++h) {
            // expand current slice, half h (VALU work also hides load latency)
            bf16x8 a[2];
            #pragma unroll
            for (int m = 0; m < 2; ++m) {
                unsigned int d0 = h ? aS[cur][m].z : aS[cur][m].x;
                unsigned int d1 = h ? aS[cur][m].w : aS[cur][m].y;
                a[m] = expand(d0, d1, sc[m][j]);
            }
            const int kk = j * 2 + h;
            #pragma unroll
            for (int t = 0; t < 4; ++t) {
                // B from LDS: lane-contiguous 16B -> 2-way bank alias (free)
                bf16x8 b = *reinterpret_cast<const bf16x8*>(
                        &wlds[((size_t)(kk * 4 + t) * 64 + lane) * 8]);
                #pragma unroll
                for (int m = 0; m < 2; ++m)
                    acc[m][t] = __builtin_amdgcn_mfma_f32_16x16x32_bf16(
                            a[m], b, acc[m][t], 0, 0, 0);
            }
        }
        __builtin_amdgcn_sched_barrier(0);   // MFMAs can't float up either
    }

    // --- epilogue: transpose through LDS for fully-coalesced 1KB stores ----
    __syncthreads();                       // all waves done reading W
    float* ldsf = reinterpret_cast<float*>(wlds);
    const int rbase = wave * 2048;
    // C/D layout: col = lane&15, row = (lane>>4)*4 + r   [measured m89/m91]
    #pragma unroll
    for (int m = 0; m < 2; ++m)
        #pragma unroll
        for (int t = 0; t < 4; ++t)
            #pragma unroll
            for (int r = 0; r < 4; ++r)
                ldsf[rbase + (m * 16 + hi * 4 + r) * 64 + t * 16 + lo] =
                        acc[m][t][r];
    __syncthreads();
    #pragma unroll
    for (int p = 0; p < 8; ++p) {
        const int f = p * 256 + lane * 4;
        f32x4 v = *reinterpret_cast<const f32x4*>(&ldsf[rbase + f]);
        *reinterpret_cast<f32x4*>(&out[(size_t)wcell * F + f]) = v;
    }
}

// ---------------- correctness-only fallback (no workspace) ----------------
__global__ void naive_kernel(const float* __restrict__ x,
                             const int* __restrict__ adjc,
                             const float* __restrict__ W,
                             float* __restrict__ out) {
    int n = blockIdx.x;
    int o = threadIdx.x;  // 64 threads
    float acc = 0.f;
    for (int j = 0; j < NH; ++j) {
        int idx = adjc[(size_t)n * NH + j];
        for (int f = 0; f < F; ++f)
            acc += x[(size_t)idx * F + f] * W[(size_t)(j * F + f) * F + o];
    }
    out[(size_t)n * F + o] = acc;
}

extern "C" void kernel_launch(void* const* d_in, const int* in_sizes, int n_in,
                              void* d_out, int out_size, void* d_ws, size_t ws_size,
                              hipStream_t stream) {
    const float* x    = (const float*)d_in[0];
    const int*   adjc = (const int*)d_in[1];
    const float* W    = (const float*)d_in[2];
    float* out = (float*)d_out;

    const size_t need_xq = (size_t)N_CELLS * F;                      // 12.58 MB
    const size_t need_s  = (size_t)N_CELLS * sizeof(float);          // 0.79 MB
    const size_t need_w  = (size_t)K_TOT * F * sizeof(unsigned short); // 72 KB

    if (ws_size >= need_xq + need_s + need_w) {
        signed char*    xq   = (signed char*)d_ws;
        float*          stab = (float*)((char*)d_ws + need_xq);
        unsigned short* wb   = (unsigned short*)((char*)d_ws + need_xq + need_s);
        convert_x_i8<<<(N_CELLS * 16) / 256, 256, 0, stream>>>(x, xq, stab);
        convert_w_kernel<<<(K_STEPS * 4 * 64) / 256, 256, 0, stream>>>(W, wb);
        fused_gather_gemm_v9<<<N_CELLS / 256, BLOCK, 0, stream>>>(
                xq, stab, adjc, wb, out);
    } else {
        naive_kernel<<<N_CELLS, F, 0, stream>>>(x, adjc, W, out);
    }
}